// Round 1
// baseline (702.635 us; speedup 1.0000x reference)
//
#include <hip/hip_runtime.h>

// Problem: penalty = (1/10) * sum_j trace(cov(class j)), unbiased (n-1).
// One-pass form: trace_j = (Sum_{i in j} ||x_i||^2 - Sum_d S_{j,d}^2 / n_j) / (n_j - 1)
// where S_{j,d} = per-class per-feature sums. Memory-bound: read 512MB of x once.

#define NCLS 10
#define DFEAT 128
#define NB 1024          // blocks for the main pass
#define BLK 256          // threads per block (8 row-groups of 32 lanes)
#define NGRP (NB * (BLK / 32))   // 8192 global row-groups
#define COLS (NCLS * 130)        // per class: 128 sums + sumsq + count -> 1300

__global__ __launch_bounds__(BLK) void k_partial(const float* __restrict__ x,
                                                 const int* __restrict__ t,
                                                 float* __restrict__ partial,
                                                 int N) {
    const int tid = threadIdx.x;
    const int lane32 = tid & 31;
    const int group = blockIdx.x * (BLK / 32) + (tid >> 5);
    const float4* __restrict__ xv = (const float4*)x;  // row stride = 32 float4

    float4 s[NCLS];
    float sq[NCLS], cn[NCLS];
#pragma unroll
    for (int c = 0; c < NCLS; ++c) {
        s[c] = make_float4(0.f, 0.f, 0.f, 0.f);
        sq[c] = 0.f;
        cn[c] = 0.f;
    }

    for (int row = group; row < N; row += NGRP) {
        float4 v = xv[row * 32 + lane32];
        int cls = t[row];  // uniform across the 32-lane group
        float d2 = v.x * v.x + v.y * v.y + v.z * v.z + v.w * v.w;
#pragma unroll
        for (int c = 0; c < NCLS; ++c) {
            if (cls == c) {
                s[c].x += v.x;
                s[c].y += v.y;
                s[c].z += v.z;
                s[c].w += v.w;
                sq[c] += d2;
                cn[c] += 1.0f;  // 32 lanes each add 1 -> totals are 32*n_j
            }
        }
    }

    // ---- block-level reduction into LDS ----
    __shared__ float smem[COLS];
    for (int i = tid; i < COLS; i += BLK) smem[i] = 0.0f;
    __syncthreads();

#pragma unroll
    for (int c = 0; c < NCLS; ++c) {
        // per-feature sums: 8 threads/block share each address (one per group)
        atomicAdd(&smem[c * 130 + lane32 * 4 + 0], s[c].x);
        atomicAdd(&smem[c * 130 + lane32 * 4 + 1], s[c].y);
        atomicAdd(&smem[c * 130 + lane32 * 4 + 2], s[c].z);
        atomicAdd(&smem[c * 130 + lane32 * 4 + 3], s[c].w);
        // sq/cn: reduce within the 32-lane group first, then 1 atomic per group
        float q = sq[c], n = cn[c];
        for (int off = 16; off > 0; off >>= 1) {
            q += __shfl_down(q, off, 32);
            n += __shfl_down(n, off, 32);
        }
        if (lane32 == 0) {
            atomicAdd(&smem[c * 130 + 128], q);
            atomicAdd(&smem[c * 130 + 129], n);
        }
    }
    __syncthreads();

    // column-major partials: partial[col][block] for coalesced stage-2 reads
    for (int i = tid; i < COLS; i += BLK)
        partial[(size_t)i * NB + blockIdx.x] = smem[i];
}

__global__ __launch_bounds__(64) void k_colsum(const float* __restrict__ partial,
                                               float* __restrict__ totals) {
    const int col = blockIdx.x;
    const float* p = partial + (size_t)col * NB;
    float v = 0.f;
    for (int i = threadIdx.x; i < NB; i += 64) v += p[i];
#pragma unroll
    for (int off = 32; off > 0; off >>= 1) v += __shfl_down(v, off, 64);
    if (threadIdx.x == 0) totals[col] = v;
}

__global__ __launch_bounds__(64) void k_final(const float* __restrict__ totals,
                                              float* __restrict__ out) {
    const int lane = threadIdx.x;
    float tr = 0.0f;
    if (lane < NCLS) {
        const float* b = totals + lane * 130;
        float ss = 0.f;
        for (int d = 0; d < DFEAT; ++d) {
            float u = b[d];
            ss += u * u;
        }
        float S2 = b[128];
        float n = b[129] * (1.0f / 32.0f);  // undo the x32 lane replication
        tr = (S2 - ss / n) / (n - 1.0f);
    }
#pragma unroll
    for (int off = 32; off > 0; off >>= 1) tr += __shfl_down(tr, off, 64);
    if (lane == 0) out[0] = tr / (float)NCLS;
}

extern "C" void kernel_launch(void* const* d_in, const int* in_sizes, int n_in,
                              void* d_out, int out_size, void* d_ws, size_t ws_size,
                              hipStream_t stream) {
    const float* x = (const float*)d_in[0];
    const int* t = (const int*)d_in[1];
    const int N = in_sizes[1];  // t has N elements; x has N*128

    float* partial = (float*)d_ws;                       // COLS * NB floats
    float* totals = partial + (size_t)COLS * NB;         // COLS floats
    float* out = (float*)d_out;

    k_partial<<<NB, BLK, 0, stream>>>(x, t, partial, N);
    k_colsum<<<COLS, 64, 0, stream>>>(partial, totals);
    k_final<<<1, 64, 0, stream>>>(totals, out);
}